// Round 1
// baseline (137.814 us; speedup 1.0000x reference)
//
#include <hip/hip_runtime.h>
#include <hip/hip_bf16.h>

// NCE / NT-Xent loss, B=4096, D=256, temp=0.5.
// loss = mean_i( log(sum_{j!=i} exp(sim_ij)) - sim_{i,(i+B)%N} ), N=8192.
// Key simplification: |sim| <= 1/temp = 2  =>  exp(sim) <= e^2, no online max needed.

constexpr int kN  = 8192;        // 2B rows
constexpr int kD  = 256;         // embedding dim
constexpr int kBH = 4096;        // B
constexpr int kChunks  = 8;      // column split for k_simlse
constexpr int kColsPer = kN / kChunks;            // 1024
constexpr float kInvTemp = 2.0f;                  // 1/temp
constexpr float kInvTempLog2e = 2.8853900817779268f; // (1/temp)*log2(e)

typedef __attribute__((ext_vector_type(8))) short bf16x8;  // 8 bf16 = 4 VGPRs
typedef __attribute__((ext_vector_type(4))) float f32x4;

__device__ __forceinline__ unsigned short f2bf(float f) {
  union { float f; unsigned u; } x;
  x.f = f;
  unsigned u = x.u;
  return (unsigned short)((u + 0x7FFFu + ((u >> 16) & 1u)) >> 16);
}

// ---------------- kernel 1: row-normalize, fp32 -> bf16 -------------------
// One wave per row; lane loads float4 (16B), shfl-reduce sum of squares.
__global__ void k_normalize(const float* __restrict__ e1,
                            const float* __restrict__ e2,
                            unsigned short* __restrict__ zn) {
  const int wave = threadIdx.x >> 6;
  const int lane = threadIdx.x & 63;
  const int row  = blockIdx.x * 4 + wave;
  const float* src = (row < kBH) ? (e1 + (size_t)row * kD)
                                 : (e2 + (size_t)(row - kBH) * kD);
  float4 v = *reinterpret_cast<const float4*>(src + lane * 4);
  float ssq = v.x * v.x + v.y * v.y + v.z * v.z + v.w * v.w;
#pragma unroll
  for (int m = 1; m < 64; m <<= 1) ssq += __shfl_xor(ssq, m);
  // norms ~16 for N(0,1) data; eps=1e-8 on the *product* can never bind.
  const float inv = 1.0f / sqrtf(ssq);
  ushort4 o;
  o.x = f2bf(v.x * inv);
  o.y = f2bf(v.y * inv);
  o.z = f2bf(v.z * inv);
  o.w = f2bf(v.w * inv);
  *reinterpret_cast<ushort4*>(zn + (size_t)row * kD + lane * 4) = o;
}

// ---------------- kernel 2: fused Z.Z^T + per-row sum(exp) ----------------
// Grid: 64 row-tiles (128 rows each) x 8 col-chunks (1024 cols each) = 512.
// Block: 4 waves; wave w owns rows [rt*128 + w*32, +32) as two 16-row
// MFMA subtiles (A kept in registers, two independent acc chains).
// B fragments stream from global (Zn = 4MB, L2-resident).
__global__ __launch_bounds__(256, 2)
void k_simlse(const unsigned short* __restrict__ zn,
              float* __restrict__ s_part,
              float* __restrict__ pos_part) {
  const int bid = blockIdx.x;
  const int rt  = bid >> 3;   // row tile 0..63
  const int ch  = bid & 7;    // column chunk 0..7
  const int wave = threadIdx.x >> 6;
  const int lane = threadIdx.x & 63;
  const int l15 = lane & 15;
  const int lhi = lane >> 4;
  const int rowBase = rt * 128 + wave * 32;
  const int colBase = ch * kColsPer;

  // A fragments: lane holds Z[row16 + (lane&15)][k0 + (lane>>4)*8 .. +7]
  bf16x8 a[2][8];
#pragma unroll
  for (int s = 0; s < 2; ++s) {
    const unsigned short* ap =
        zn + (size_t)(rowBase + s * 16 + l15) * kD + lhi * 8;
#pragma unroll
    for (int ks = 0; ks < 8; ++ks)
      a[s][ks] = *reinterpret_cast<const bf16x8*>(ap + ks * 32);
  }

  float sacc[2][4] = {{0.f, 0.f, 0.f, 0.f}, {0.f, 0.f, 0.f, 0.f}};
  float pacc[2][4] = {{0.f, 0.f, 0.f, 0.f}, {0.f, 0.f, 0.f, 0.f}};

  for (int ct = 0; ct < kColsPer / 16; ++ct) {
    const int cb = colBase + ct * 16;
    const unsigned short* bp = zn + (size_t)(cb + l15) * kD + lhi * 8;
    bf16x8 b[8];
#pragma unroll
    for (int ks = 0; ks < 8; ++ks)
      b[ks] = *reinterpret_cast<const bf16x8*>(bp + ks * 32);

    f32x4 acc0 = {0.f, 0.f, 0.f, 0.f};
    f32x4 acc1 = {0.f, 0.f, 0.f, 0.f};
#pragma unroll
    for (int ks = 0; ks < 8; ++ks) {
      acc0 = __builtin_amdgcn_mfma_f32_16x16x32_bf16(a[0][ks], b[ks], acc0, 0, 0, 0);
      acc1 = __builtin_amdgcn_mfma_f32_16x16x32_bf16(a[1][ks], b[ks], acc1, 0, 0, 0);
    }

    const int c = cb + l15;  // this lane's column (C/D layout: col = lane&15)
#pragma unroll
    for (int s = 0; s < 2; ++s) {
      const f32x4 acc = s ? acc1 : acc0;
      const int rbase16 = rowBase + s * 16;
      const bool diagT = (cb == rbase16);                       // wave-uniform
      const bool posT  = (cb == ((rbase16 + kBH) & (kN - 1)));  // wave-uniform
      if (!diagT && !posT) {
#pragma unroll
        for (int j = 0; j < 4; ++j)
          sacc[s][j] += exp2f(acc[j] * kInvTempLog2e);
      } else {
#pragma unroll
        for (int j = 0; j < 4; ++j) {
          const int row = rbase16 + lhi * 4 + j;  // C/D: row=(lane>>4)*4+j
          const float v = acc[j] * kInvTemp;
          float p = exp2f(acc[j] * kInvTempLog2e);
          if (diagT && c == row) p = 0.0f;                       // mask diagonal
          if (posT && c == ((row + kBH) & (kN - 1))) pacc[s][j] += v;
          sacc[s][j] += p;
        }
      }
    }
  }

  // Reduce across the 16-lane column group; lane with (lane&15)==0 stores.
#pragma unroll
  for (int s = 0; s < 2; ++s) {
#pragma unroll
    for (int j = 0; j < 4; ++j) {
      float sv = sacc[s][j];
      float pv = pacc[s][j];
#pragma unroll
      for (int m = 1; m < 16; m <<= 1) {
        sv += __shfl_xor(sv, m);
        pv += __shfl_xor(pv, m);
      }
      if (l15 == 0) {
        const int row = rowBase + s * 16 + lhi * 4 + j;
        s_part[ch * kN + row]   = sv;
        pos_part[ch * kN + row] = pv;
      }
    }
  }
}

// ---------------- kernel 3: fold chunks, log, final reduce ----------------
__global__ void k_final(const float* __restrict__ s_part,
                        const float* __restrict__ pos_part,
                        float* __restrict__ out) {
  __shared__ float red[16];
  float acc = 0.0f;
  for (int r = threadIdx.x; r < kN; r += 1024) {
    float sv = 0.0f, pv = 0.0f;
#pragma unroll
    for (int h = 0; h < kChunks; ++h) {
      sv += s_part[h * kN + r];
      pv += pos_part[h * kN + r];
    }
    acc += logf(sv) - pv;
  }
#pragma unroll
  for (int m = 1; m < 64; m <<= 1) acc += __shfl_xor(acc, m);
  const int wave = threadIdx.x >> 6;
  const int lane = threadIdx.x & 63;
  if (lane == 0) red[wave] = acc;
  __syncthreads();
  if (threadIdx.x == 0) {
    float t = 0.0f;
#pragma unroll
    for (int w = 0; w < 16; ++w) t += red[w];
    out[0] = t / (float)kN;
  }
}

extern "C" void kernel_launch(void* const* d_in, const int* in_sizes, int n_in,
                              void* d_out, int out_size, void* d_ws, size_t ws_size,
                              hipStream_t stream) {
  const float* e1 = (const float*)d_in[0];
  const float* e2 = (const float*)d_in[1];
  float* out = (float*)d_out;

  // ws layout: [Zn bf16: N*D*2 = 4MB][s_part: 8*N*4][pos_part: 8*N*4] ~ 4.75MB
  unsigned short* zn = (unsigned short*)d_ws;
  float* s_part   = (float*)((char*)d_ws + (size_t)kN * kD * 2);
  float* pos_part = s_part + kChunks * kN;

  hipLaunchKernelGGL(k_normalize, dim3(kN / 4), dim3(256), 0, stream, e1, e2, zn);
  hipLaunchKernelGGL(k_simlse, dim3(64 * kChunks), dim3(256), 0, stream,
                     zn, s_part, pos_part);
  hipLaunchKernelGGL(k_final, dim3(1), dim3(1024), 0, stream,
                     s_part, pos_part, out);
}